// Round 6
// baseline (444.583 us; speedup 1.0000x reference)
//
#include <hip/hip_runtime.h>
#include <hip/hip_bf16.h>
#include <math.h>

#define B_  32
#define S_  512
#define D_  512
#define E_  8
#define H_  2048
#define O_  512

typedef __bf16 bf16x8 __attribute__((ext_vector_type(8)));
typedef float  f32x4  __attribute__((ext_vector_type(4)));

#define GL2LDS(src, dst) \
  __builtin_amdgcn_global_load_lds((const __attribute__((address_space(1))) void*)(src), \
                                   (__attribute__((address_space(3))) void*)(dst), 16, 0, 0)

// tanh-form GELU (proven r4/r5: absmax unchanged at 3.9e-3)
__device__ __forceinline__ float gelu_fast(float v) {
  float w = v * fmaf(v * v, 0.0713548162f, 1.5957691216f);
  float e = __expf(-w);
  return v * __builtin_amdgcn_rcpf(1.0f + e);
}

// ---------------- cast x -> bf16, fused attention scores ----------------
__global__ __launch_bounds__(256) void cast_score_kernel(
    const float* __restrict__ x, const float* __restrict__ attn_w,
    ushort* __restrict__ xb, float* __restrict__ scores)
{
  const int t = threadIdx.x;
  const int r = t >> 5;
  const int cg = t & 31;
  const int row = blockIdx.x * 8 + r;
  const float* src  = x + (size_t)row * D_ + cg * 16;
  const float* wsrc = attn_w + cg * 16;
  ushort* dstp = xb + (size_t)row * D_ + cg * 16;
  float acc = 0.f;
#pragma unroll
  for (int k = 0; k < 4; ++k) {
    float4 v  = *(const float4*)(src + k * 4);
    float4 wv = *(const float4*)(wsrc + k * 4);
    acc += v.x * wv.x + v.y * wv.y + v.z * wv.z + v.w * wv.w;
    ushort4 o;
    o.x = __builtin_bit_cast(unsigned short, __float2bfloat16(v.x));
    o.y = __builtin_bit_cast(unsigned short, __float2bfloat16(v.y));
    o.z = __builtin_bit_cast(unsigned short, __float2bfloat16(v.z));
    o.w = __builtin_bit_cast(unsigned short, __float2bfloat16(v.w));
    *(ushort4*)(dstp + k * 4) = o;
  }
#pragma unroll
  for (int off = 16; off; off >>= 1) acc += __shfl_xor(acc, off);
  if (cg == 0) scores[row] = acc;
}

// ---------------- softmax over S per batch -> aw ----------------
__global__ __launch_bounds__(512) void softmax_aw_kernel(
    const float* __restrict__ scores, float* __restrict__ aw)
{
  __shared__ float red[8];
  __shared__ float mm, ss;
  const int t = threadIdx.x, b = blockIdx.x;
  float v = scores[b * S_ + t];
  float m = v;
#pragma unroll
  for (int off = 32; off; off >>= 1) m = fmaxf(m, __shfl_xor(m, off));
  if ((t & 63) == 0) red[t >> 6] = m;
  __syncthreads();
  if (t == 0) {
    float a = red[0];
    for (int i = 1; i < 8; ++i) a = fmaxf(a, red[i]);
    mm = a;
  }
  __syncthreads();
  float e = expf(v - mm);
  float s = e;
#pragma unroll
  for (int off = 32; off; off >>= 1) s += __shfl_xor(s, off);
  if ((t & 63) == 0) red[t >> 6] = s;
  __syncthreads();
  if (t == 0) {
    float a = 0.f;
    for (int i = 0; i < 8; ++i) a += red[i];
    ss = 1.f / a;
  }
  __syncthreads();
  aw[b * S_ + t] = e * ss;
}

// ---------------- pooled[b,d] = sum_s aw[b,s] * x[b,s,d] (f32, exact) ----------------
__global__ __launch_bounds__(512) void pool_kernel(
    const float* __restrict__ x, const float* __restrict__ aw, float* __restrict__ pooled)
{
  __shared__ float sm[4][128];
  const int t = threadIdx.x;
  const int dl = t & 127;
  const int sh = t >> 7;
  const int b = blockIdx.y;
  const int d = blockIdx.x * 128 + dl;
  const float* xp  = x + (size_t)b * S_ * D_ + d;
  const float* awb = aw + b * S_;
  float acc = 0.f;
#pragma unroll 4
  for (int s = sh; s < S_; s += 4)
    acc = fmaf(awb[s], xp[(size_t)s * D_], acc);
  if (sh) sm[sh][dl] = acc;
  __syncthreads();
  if (sh == 0) pooled[b * D_ + d] = acc + sm[1][dl] + sm[2][dl] + sm[3][dl];
}

// ---------------- gates + top-2 + renorm + expert-sort ----------------
__global__ __launch_bounds__(256) void gate_psort_kernel(
    const float* __restrict__ pooled, const float* __restrict__ gate_w,
    const float* __restrict__ gate_b, int* __restrict__ gidx, float* __restrict__ gwt,
    int* __restrict__ psort)
{
  __shared__ float gl[32][8];
  const int t = threadIdx.x;
  const int b = t >> 3, ee = t & 7;
  float z = gate_b[ee];
  const float* pb = pooled + b * D_;
  for (int d = 0; d < D_; ++d) z = fmaf(pb[d], gate_w[d * E_ + ee], z);
  gl[b][ee] = z;
  __syncthreads();
  if (t < 32) {
    float ge[8];
    float zmax = gl[t][0];
    for (int i = 1; i < 8; ++i) zmax = fmaxf(zmax, gl[t][i]);
    float zs = 0.f;
    for (int i = 0; i < 8; ++i) { ge[i] = expf(gl[t][i] - zmax); zs += ge[i]; }
    for (int i = 0; i < 8; ++i) ge[i] /= zs;
    int i0 = 0;
    for (int i = 1; i < 8; ++i) if (ge[i] > ge[i0]) i0 = i;
    int i1 = -1;
    for (int i = 0; i < 8; ++i) if (i != i0 && (i1 < 0 || ge[i] > ge[i1])) i1 = i;
    float denom = ge[i0] + ge[i1] + 1e-9f;
    gidx[t * 2 + 0] = i0; gidx[t * 2 + 1] = i1;
    gwt[t * 2 + 0] = ge[i0] / denom; gwt[t * 2 + 1] = ge[i1] / denom;
  }
  __syncthreads();
  if (t == 0) {
    int cnt[E_] = {}, pos[E_];
    for (int p = 0; p < 2 * B_; ++p) cnt[gidx[p]]++;
    int s = 0;
    for (int e2 = 0; e2 < E_; ++e2) { pos[e2] = s; s += cnt[e2]; }
    for (int p = 0; p < 2 * B_; ++p) psort[pos[gidx[p]]++] = p;
  }
}

// ---------------- [z][R][C] f32 -> [z][C][R] bf16 ----------------
__global__ void transpose_cast_kernel(const float* __restrict__ in,
                                      __hip_bfloat16* __restrict__ outT, int R, int C)
{
  __shared__ float tile[32][33];
  const int z = blockIdx.z;
  const float* inz = in + (size_t)z * R * C;
  __hip_bfloat16* outz = outT + (size_t)z * R * C;
  const int c0 = blockIdx.x * 32, r0 = blockIdx.y * 32;
  const int tx = threadIdx.x, ty = threadIdx.y;
#pragma unroll
  for (int jj = 0; jj < 4; ++jj) {
    int r = r0 + ty + jj * 8;
    tile[ty + jj * 8][tx] = inz[(size_t)r * C + c0 + tx];
  }
  __syncthreads();
#pragma unroll
  for (int jj = 0; jj < 4; ++jj) {
    int c = c0 + ty + jj * 8;
    outz[(size_t)c * R + r0 + tx] = __float2bfloat16(tile[tx][ty + jj * 8]);
  }
}

// =====================================================================
// GEMM core v2: 256(A=weight rows -> out features) x 256(B=data rows) x BK=32.
// 512 threads = 8 waves: wr=w>>2 (A-half, 128 rows), wc=w&3 (B-quarter, 64).
// acc[8][4]; 32 independent MFMA per tile; 12 ds_read_b128 per wave per tile
// (4 B-frags shared across all 8 A-frags).
// LDS: 3-deep ring of 32 KB slots (A 16KB rows 0..255 x 64B, B 16KB at +16K).
// Swizzle: byte ^= (((row>>1)&3)<<4)  -> uniform 2-way bank access (free),
// involution applied on pre-swizzled global source (GL2LDS linear dest).
// Ring: iter t reads slot t%3, stages tile t+2 into slot (t+2)%3 (WAR-free
// by construction). Counted vmcnt(8)/(4)/(0); 2 barriers/iter; one fully
// compiler-scheduled region {stage || reads || MFMA} per tile (no mid pins).
// =====================================================================
__device__ __forceinline__ void gemm_core32(const char* __restrict__ Wg, const char* __restrict__ Xg,
                                            const int ldw, const int ldx, const int NT,
                                            char* lds, f32x4 (&acc)[8][4])
{
  const int tid = threadIdx.x;
  const int l = tid & 63;
  const int w = tid >> 6;
  const int wr = w >> 2;                   // A half (128 rows)
  const int wc = w & 3;                    // B quarter (64 rows)
  const int lr = l & 15;
  const int ks = (l >> 4) & 3;             // 16B k-slot within 64B row
  const int swz = (ks ^ ((lr >> 1) & 3)) << 4;
  const int abase = (wr * 128 + lr) * 64 + swz;           // + m*1024
  const int bbase = 16384 + (wc * 64 + lr) * 64 + swz;    // + n*1024

  // staging: thread -> (row = tid>>2 [+128 for chunk 1], 16B slot = tid&3)
  const int rw = tid >> 2;
  const int scol = (((tid & 3) ^ ((tid >> 3) & 3)) << 4); // inverse-swizzled src col
  const int dst = tid * 16;
  const char* sA0 = Wg + (size_t)rw * ldw + scol;
  const char* sA1 = Wg + (size_t)(rw + 128) * ldw + scol;
  const char* sB0 = Xg + (size_t)rw * ldx + scol;
  const char* sB1 = Xg + (size_t)(rw + 128) * ldx + scol;

#define STAGE32(kt, sp) { \
    const size_t ko = (size_t)(kt) * 64; \
    GL2LDS(sA0 + ko, (sp) + dst); \
    GL2LDS(sA1 + ko, (sp) + 8192 + dst); \
    GL2LDS(sB0 + ko, (sp) + 16384 + dst); \
    GL2LDS(sB1 + ko, (sp) + 24576 + dst); }

  STAGE32(0, lds);
  STAGE32(1, lds + 32768);

#pragma unroll 1
  for (int t = 0; t < NT; ++t) {
    char* cur = lds + (t % 3) * 32768;
    if (t + 2 < NT) {                      // stage 2 tiles ahead (ring slot free since iter t-1)
      char* nb = lds + ((t + 2) % 3) * 32768;
      STAGE32(t + 2, nb);
      asm volatile("s_waitcnt vmcnt(8)" ::: "memory");   // drain tile t's 4 loads
    } else if (t + 1 < NT) {
      asm volatile("s_waitcnt vmcnt(4)" ::: "memory");
    } else {
      asm volatile("s_waitcnt vmcnt(0)" ::: "memory");
    }
    __builtin_amdgcn_s_barrier();          // all waves' tile-t staging landed
    __builtin_amdgcn_sched_barrier(0);

    bf16x8 af[8], bfv[4];
#pragma unroll
    for (int n = 0; n < 4; ++n) bfv[n] = *(const bf16x8*)(cur + bbase + n * 1024);
#pragma unroll
    for (int m = 0; m < 8; ++m) af[m] = *(const bf16x8*)(cur + abase + m * 1024);
    __builtin_amdgcn_s_setprio(1);
#pragma unroll
    for (int m = 0; m < 8; ++m)
#pragma unroll
      for (int n = 0; n < 4; ++n)
        acc[m][n] = __builtin_amdgcn_mfma_f32_16x16x32_bf16(af[m], bfv[n], acc[m][n], 0, 0, 0);
    __builtin_amdgcn_s_setprio(0);

    __builtin_amdgcn_sched_barrier(0);
    __builtin_amdgcn_s_barrier();          // tile-t reads done -> slot may be re-staged
  }
#undef STAGE32
}

// ---------------- GEMM1: H[p][s][h] = gelu(x @ w1 + b1), bf16 ----------------
__global__ __launch_bounds__(512, 2) void gemm1_kernel(
    const __hip_bfloat16* __restrict__ Xb, const __hip_bfloat16* __restrict__ W1T,
    const float* __restrict__ b1, __hip_bfloat16* __restrict__ Hbuf,
    const int* __restrict__ gidx, const int* __restrict__ psort)
{
  extern __shared__ char lds[];
  const int P = blockIdx.x;                 // 1024 blocks
  const int L = (P & 7) * 128 + (P >> 3);   // bijective XCD chunk remap
  const int p = psort[L >> 4];              // 16 tiles/pair, pair-clustered per XCD
  const int tl = L & 15;
  const int b = p >> 1;
  const int e = gidx[p];
  const int h0 = (tl >> 1) * 256;           // 8 h-tiles
  const int s0 = (tl & 1) * 256;            // 2 s-tiles
  const char* Wg = (const char*)W1T + ((size_t)e * H_ + h0) * D_ * 2;
  const char* Xg = (const char*)Xb + ((size_t)b * S_ + s0) * D_ * 2;
  f32x4 acc[8][4] = {};
  gemm_core32(Wg, Xg, D_ * 2, D_ * 2, D_ / 32, lds, acc);

  const int tid = threadIdx.x, l = tid & 63, w = tid >> 6;
  const int wr = w >> 2, wc = w & 3, lr = l & 15, q4 = ((l >> 4) & 3) << 2;
  const float* b1e = b1 + (size_t)e * H_ + h0;
  __hip_bfloat16* Hp = Hbuf + (size_t)p * S_ * H_ + h0;
#pragma unroll
  for (int m = 0; m < 8; ++m) {
    const int hl = wr * 128 + m * 16 + q4;          // feature offset (mult of 4)
    const float4 bias = *(const float4*)(b1e + hl);
#pragma unroll
    for (int n = 0; n < 4; ++n) {
      const int sl = s0 + wc * 64 + n * 16 + lr;    // s row
      ushort4 ov;
      ov.x = __builtin_bit_cast(unsigned short, __float2bfloat16(gelu_fast(acc[m][n][0] + bias.x)));
      ov.y = __builtin_bit_cast(unsigned short, __float2bfloat16(gelu_fast(acc[m][n][1] + bias.y)));
      ov.z = __builtin_bit_cast(unsigned short, __float2bfloat16(gelu_fast(acc[m][n][2] + bias.z)));
      ov.w = __builtin_bit_cast(unsigned short, __float2bfloat16(gelu_fast(acc[m][n][3] + bias.w)));
      *(ushort4*)(Hp + (size_t)sl * H_ + hl) = ov;
    }
  }
}

// ---------------- GEMM2: out[b][s][o] += gw * gelu(H @ w2 + b2) (atomic, 2 terms) ----
__global__ __launch_bounds__(512, 2) void gemm2_kernel(
    const __hip_bfloat16* __restrict__ Hbuf, const __hip_bfloat16* __restrict__ W2T,
    const float* __restrict__ b2, float* __restrict__ out,
    const int* __restrict__ gidx, const float* __restrict__ gwt,
    const int* __restrict__ psort)
{
  extern __shared__ char lds[];
  const int P = blockIdx.x;                 // 256 blocks (1/CU)
  const int L = (P & 7) * 32 + (P >> 3);
  const int p = psort[L >> 2];              // 4 tiles/pair, expert-clustered per XCD
  const int tl = L & 3;
  const int b = p >> 1;
  const int e = gidx[p];
  const float gw = gwt[p];
  const int o0 = (tl >> 1) * 256;           // 2 o-tiles
  const int s0 = (tl & 1) * 256;            // 2 s-tiles
  const char* Wg = (const char*)W2T + ((size_t)e * O_ + o0) * H_ * 2;
  const char* Xg = (const char*)Hbuf + ((size_t)p * S_ + s0) * H_ * 2;
  f32x4 acc[8][4] = {};
  gemm_core32(Wg, Xg, H_ * 2, H_ * 2, H_ / 32, lds, acc);

  const int tid = threadIdx.x, l = tid & 63, w = tid >> 6;
  const int wr = w >> 2, wc = w & 3, lr = l & 15, q4 = ((l >> 4) & 3) << 2;
  const float* b2e = b2 + (size_t)e * O_ + o0;
#pragma unroll
  for (int m = 0; m < 8; ++m) {
    const int ol = wr * 128 + m * 16 + q4;
    const float4 bias = *(const float4*)(b2e + ol);
#pragma unroll
    for (int n = 0; n < 4; ++n) {
      const int sl = s0 + wc * 64 + n * 16 + lr;
      float* dstp = out + ((size_t)b * S_ + sl) * O_ + o0 + ol;
      atomicAdd(dstp + 0, gelu_fast(acc[m][n][0] + bias.x) * gw);
      atomicAdd(dstp + 1, gelu_fast(acc[m][n][1] + bias.y) * gw);
      atomicAdd(dstp + 2, gelu_fast(acc[m][n][2] + bias.z) * gw);
      atomicAdd(dstp + 3, gelu_fast(acc[m][n][3] + bias.w) * gw);
    }
  }
}

// ---------------- sentinel (ws too small signal) ----------------
__global__ void sentinel_kernel(float* out, int n) {
  int i = blockIdx.x * blockDim.x + threadIdx.x;
  for (; i < n; i += gridDim.x * blockDim.x) out[i] = 1.0e6f;
}

extern "C" void kernel_launch(void* const* d_in, const int* in_sizes, int n_in,
                              void* d_out, int out_size, void* d_ws, size_t ws_size,
                              hipStream_t stream)
{
  const float* x      = (const float*)d_in[0];
  const float* attn_w = (const float*)d_in[1];
  // d_in[2] = attn_b: scalar, softmax-invariant -> unused
  const float* gate_w = (const float*)d_in[3];
  const float* gate_b = (const float*)d_in[4];
  const float* w1     = (const float*)d_in[5];
  const float* b1     = (const float*)d_in[6];
  const float* w2     = (const float*)d_in[7];
  const float* b2     = (const float*)d_in[8];
  float* out = (float*)d_out;

  char* ws = (char*)d_ws;
  const size_t OFF_GIDX = 0;     // 256 B
  const size_t OFF_GWT  = 256;   // 256 B
  const size_t OFF_PSRT = 512;   // 256 B
  const size_t OFF_X    = 1024;
  const size_t SZ_X     = (size_t)B_ * S_ * D_ * 2;   // 16 MB
  const size_t OFF_W1T  = OFF_X + SZ_X;
  const size_t SZ_W1T   = (size_t)E_ * H_ * D_ * 2;   // 16 MB
  const size_t OFF_W2T  = OFF_W1T + SZ_W1T;
  const size_t SZ_W2T   = (size_t)E_ * O_ * H_ * 2;   // 16 MB
  const size_t OFF_H    = OFF_W2T + SZ_W2T;
  const size_t PAIR_H   = (size_t)S_ * H_ * 2;        // 2 MB per pair

  if (OFF_H + 64 * PAIR_H > ws_size) {
    hipLaunchKernelGGL(sentinel_kernel, dim3(256), dim3(256), 0, stream, out, out_size);
    return;
  }

  int*   gidx  = (int*)(ws + OFF_GIDX);
  float* gwt   = (float*)(ws + OFF_GWT);
  int*   psort = (int*)(ws + OFF_PSRT);
  __hip_bfloat16* xb   = (__hip_bfloat16*)(ws + OFF_X);
  __hip_bfloat16* w1T  = (__hip_bfloat16*)(ws + OFF_W1T);
  __hip_bfloat16* w2T  = (__hip_bfloat16*)(ws + OFF_W2T);
  __hip_bfloat16* Hbuf = (__hip_bfloat16*)(ws + OFF_H);
  // pool-chain scratch overlaid on Hbuf region (consumed before gemm1 writes it)
  float* scores = (float*)(ws + OFF_H);            // 64 KB
  float* aw     = (float*)(ws + OFF_H + 65536);    // 64 KB
  float* pooled = (float*)(ws + OFF_H + 131072);   // 64 KB

  // 96 KiB dynamic LDS opt-in
  (void)hipFuncSetAttribute((const void*)gemm1_kernel, hipFuncAttributeMaxDynamicSharedMemorySize, 98304);
  (void)hipFuncSetAttribute((const void*)gemm2_kernel, hipFuncAttributeMaxDynamicSharedMemorySize, 98304);

  hipLaunchKernelGGL(cast_score_kernel, dim3(B_ * S_ / 8), dim3(256), 0, stream,
                     x, attn_w, (ushort*)xb, scores);
  hipLaunchKernelGGL(softmax_aw_kernel, dim3(B_), dim3(512), 0, stream, scores, aw);
  hipLaunchKernelGGL(pool_kernel, dim3(4, B_), dim3(512), 0, stream, x, aw, pooled);
  hipLaunchKernelGGL(gate_psort_kernel, dim3(1), dim3(256), 0, stream,
                     pooled, gate_w, gate_b, gidx, gwt, psort);
  hipLaunchKernelGGL(transpose_cast_kernel, dim3(H_ / 32, D_ / 32, E_), dim3(32, 8), 0, stream,
                     w1, w1T, D_, H_);
  hipLaunchKernelGGL(transpose_cast_kernel, dim3(O_ / 32, H_ / 32, E_), dim3(32, 8), 0, stream,
                     w2, w2T, H_, O_);
  hipMemsetAsync(d_out, 0, (size_t)out_size * sizeof(float), stream);

  hipLaunchKernelGGL(gemm1_kernel, dim3(1024), dim3(512), 98304, stream,
                     xb, w1T, b1, Hbuf, gidx, psort);
  hipLaunchKernelGGL(gemm2_kernel, dim3(256), dim3(512), 98304, stream,
                     Hbuf, w2T, b2, out, gidx, gwt, psort);
}

// Round 7
// 290.157 us; speedup vs baseline: 1.5322x; 1.5322x over previous
//
#include <hip/hip_runtime.h>
#include <hip/hip_bf16.h>
#include <math.h>

#define B_  32
#define S_  512
#define D_  512
#define E_  8
#define H_  2048
#define O_  512

typedef __bf16 bf16x8 __attribute__((ext_vector_type(8)));
typedef float  f32x4  __attribute__((ext_vector_type(4)));

#define GL2LDS(src, dst) \
  __builtin_amdgcn_global_load_lds((const __attribute__((address_space(1))) void*)(src), \
                                   (__attribute__((address_space(3))) void*)(dst), 16, 0, 0)

#define MFMA16(a, b, c) __builtin_amdgcn_mfma_f32_16x16x32_bf16((a), (b), (c), 0, 0, 0)

// tanh-form GELU (proven r4/r5: absmax unchanged at 3.9e-3)
__device__ __forceinline__ float gelu_fast(float v) {
  float w = v * fmaf(v * v, 0.0713548162f, 1.5957691216f);
  float e = __expf(-w);
  return v * __builtin_amdgcn_rcpf(1.0f + e);
}

// ---------------- cast x -> bf16, fused attention scores ----------------
__global__ __launch_bounds__(256) void cast_score_kernel(
    const float* __restrict__ x, const float* __restrict__ attn_w,
    ushort* __restrict__ xb, float* __restrict__ scores)
{
  const int t = threadIdx.x;
  const int r = t >> 5;
  const int cg = t & 31;
  const int row = blockIdx.x * 8 + r;
  const float* src  = x + (size_t)row * D_ + cg * 16;
  const float* wsrc = attn_w + cg * 16;
  ushort* dstp = xb + (size_t)row * D_ + cg * 16;
  float acc = 0.f;
#pragma unroll
  for (int k = 0; k < 4; ++k) {
    float4 v  = *(const float4*)(src + k * 4);
    float4 wv = *(const float4*)(wsrc + k * 4);
    acc += v.x * wv.x + v.y * wv.y + v.z * wv.z + v.w * wv.w;
    ushort4 o;
    o.x = __builtin_bit_cast(unsigned short, __float2bfloat16(v.x));
    o.y = __builtin_bit_cast(unsigned short, __float2bfloat16(v.y));
    o.z = __builtin_bit_cast(unsigned short, __float2bfloat16(v.z));
    o.w = __builtin_bit_cast(unsigned short, __float2bfloat16(v.w));
    *(ushort4*)(dstp + k * 4) = o;
  }
#pragma unroll
  for (int off = 16; off; off >>= 1) acc += __shfl_xor(acc, off);
  if (cg == 0) scores[row] = acc;
}

// ---------------- softmax over S per batch -> aw ----------------
__global__ __launch_bounds__(512) void softmax_aw_kernel(
    const float* __restrict__ scores, float* __restrict__ aw)
{
  __shared__ float red[8];
  __shared__ float mm, ss;
  const int t = threadIdx.x, b = blockIdx.x;
  float v = scores[b * S_ + t];
  float m = v;
#pragma unroll
  for (int off = 32; off; off >>= 1) m = fmaxf(m, __shfl_xor(m, off));
  if ((t & 63) == 0) red[t >> 6] = m;
  __syncthreads();
  if (t == 0) {
    float a = red[0];
    for (int i = 1; i < 8; ++i) a = fmaxf(a, red[i]);
    mm = a;
  }
  __syncthreads();
  float e = expf(v - mm);
  float s = e;
#pragma unroll
  for (int off = 32; off; off >>= 1) s += __shfl_xor(s, off);
  if ((t & 63) == 0) red[t >> 6] = s;
  __syncthreads();
  if (t == 0) {
    float a = 0.f;
    for (int i = 0; i < 8; ++i) a += red[i];
    ss = 1.f / a;
  }
  __syncthreads();
  aw[b * S_ + t] = e * ss;
}

// ---------------- pooled[b,d] = sum_s aw[b,s] * x[b,s,d] ----------------
__global__ __launch_bounds__(512) void pool_kernel(
    const float* __restrict__ x, const float* __restrict__ aw, float* __restrict__ pooled)
{
  __shared__ float sm[4][128];
  const int t = threadIdx.x;
  const int dl = t & 127;
  const int sh = t >> 7;
  const int b = blockIdx.y;
  const int d = blockIdx.x * 128 + dl;
  const float* xp  = x + (size_t)b * S_ * D_ + d;
  const float* awb = aw + b * S_;
  float acc = 0.f;
#pragma unroll 4
  for (int s = sh; s < S_; s += 4)
    acc = fmaf(awb[s], xp[(size_t)s * D_], acc);
  if (sh) sm[sh][dl] = acc;
  __syncthreads();
  if (sh == 0) pooled[b * D_ + d] = acc + sm[1][dl] + sm[2][dl] + sm[3][dl];
}

// ---------------- gates + top-2 + renorm + expert-sort ----------------
__global__ __launch_bounds__(256) void gate_psort_kernel(
    const float* __restrict__ pooled, const float* __restrict__ gate_w,
    const float* __restrict__ gate_b, int* __restrict__ gidx, float* __restrict__ gwt,
    int* __restrict__ psort)
{
  __shared__ float gl[32][8];
  const int t = threadIdx.x;
  const int b = t >> 3, ee = t & 7;
  float z = gate_b[ee];
  const float* pb = pooled + b * D_;
  for (int d = 0; d < D_; ++d) z = fmaf(pb[d], gate_w[d * E_ + ee], z);
  gl[b][ee] = z;
  __syncthreads();
  if (t < 32) {
    float ge[8];
    float zmax = gl[t][0];
    for (int i = 1; i < 8; ++i) zmax = fmaxf(zmax, gl[t][i]);
    float zs = 0.f;
    for (int i = 0; i < 8; ++i) { ge[i] = expf(gl[t][i] - zmax); zs += ge[i]; }
    for (int i = 0; i < 8; ++i) ge[i] /= zs;
    int i0 = 0;
    for (int i = 1; i < 8; ++i) if (ge[i] > ge[i0]) i0 = i;
    int i1 = -1;
    for (int i = 0; i < 8; ++i) if (i != i0 && (i1 < 0 || ge[i] > ge[i1])) i1 = i;
    float denom = ge[i0] + ge[i1] + 1e-9f;
    gidx[t * 2 + 0] = i0; gidx[t * 2 + 1] = i1;
    gwt[t * 2 + 0] = ge[i0] / denom; gwt[t * 2 + 1] = ge[i1] / denom;
  }
  __syncthreads();
  if (t == 0) {
    int cnt[E_] = {}, pos[E_];
    for (int p = 0; p < 2 * B_; ++p) cnt[gidx[p]]++;
    int s = 0;
    for (int e2 = 0; e2 < E_; ++e2) { pos[e2] = s; s += cnt[e2]; }
    for (int p = 0; p < 2 * B_; ++p) psort[pos[gidx[p]]++] = p;
  }
}

// ---------------- [z][R][C] f32 -> [z][C][R] bf16 ----------------
__global__ void transpose_cast_kernel(const float* __restrict__ in,
                                      __hip_bfloat16* __restrict__ outT, int R, int C)
{
  __shared__ float tile[32][33];
  const int z = blockIdx.z;
  const float* inz = in + (size_t)z * R * C;
  __hip_bfloat16* outz = outT + (size_t)z * R * C;
  const int c0 = blockIdx.x * 32, r0 = blockIdx.y * 32;
  const int tx = threadIdx.x, ty = threadIdx.y;
#pragma unroll
  for (int jj = 0; jj < 4; ++jj) {
    int r = r0 + ty + jj * 8;
    tile[ty + jj * 8][tx] = inz[(size_t)r * C + c0 + tx];
  }
  __syncthreads();
#pragma unroll
  for (int jj = 0; jj < 4; ++jj) {
    int c = c0 + ty + jj * 8;
    outz[(size_t)c * R + r0 + tx] = __float2bfloat16(tile[tx][ty + jj * 8]);
  }
}

// =====================================================================
// GEMM core v3: 256(A) x 256(B) x BK=64. 512 thr = 8 waves (wm 0..1 A-half,
// wn 0..3 B-quarter), per-wave out 128x64 = acc[8][4]. 2 x 64KB dbuf.
// Each K-tile = 4 stage-units (SU): A-kh0, B-kh0, A-kh1, B-kh1 (kh = 32-k
// half; SU = 256 rows x 64B = 16KB = 2 GL2LDS/thread). SUs of tile t+1 are
// issued one-per-phase AFTER that phase's barrier (targets the non-read
// buffer; WAR-safe by the P1 barrier of the next tile).
// Counted waits (exact ledger): entry-P1 queue = [A0,B0,A1,B1](t) -> vmcnt(4)
// drains A0,B0. entry-P3 queue = [A1,B1(t),A0,B0(t+1)] -> vmcnt(4) drains
// A1,B1(t). Last tile: P3 uses vmcnt(0). Prefetch distance = 1 full tile.
// LDS layout per buffer: A [2 kh][256 rows][64B] at 0, B same at 32KB.
// Slot swizzle: slot = ks ^ ((row>>1)&3) -> 16-lane frag reads cover all 32
// banks (r5-quality); inverse applied on global source col (rule #21).
// =====================================================================
__device__ __forceinline__ void gemm_core_v3(const char* __restrict__ Ag, const char* __restrict__ Bg,
                                             const int lda, const int ldb, const int NT,
                                             char* lds, f32x4 (&acc)[8][4])
{
  const int tid = threadIdx.x;
  const int l = tid & 63;
  const int w = tid >> 6;
  const int wm = w >> 2;
  const int wn = w & 3;
  const int lr = l & 15;
  const int ks = (l >> 4) & 3;
  const int axor = ((ks ^ ((lr >> 1) & 3)) << 4);
  const int abase = (wm * 128 + lr) * 64 + axor;           // + kh*16384 + m*1024
  const int bbase = 32768 + (wn * 64 + lr) * 64 + axor;    // + kh*16384 + n*1024

  const int rw = tid >> 2;                                 // 0..127
  const int sx = (((tid & 3) ^ ((rw >> 1) & 3)) << 4);     // inverse-swizzled src col
  const int dst = tid * 16;
  const char* A0p = Ag + (size_t)rw * lda + sx;
  const char* A1p = Ag + (size_t)(rw + 128) * lda + sx;    // ((rw+128)>>1)&3 == (rw>>1)&3
  const char* B0p = Bg + (size_t)rw * ldb + sx;
  const char* B1p = Bg + (size_t)(rw + 128) * ldb + sx;

#define SU_A(t, kh, bufp) { const int go = (t) * 128 + (kh) * 64; \
    GL2LDS(A0p + go, (bufp) + (kh) * 16384 + dst); \
    GL2LDS(A1p + go, (bufp) + (kh) * 16384 + 8192 + dst); }
#define SU_B(t, kh, bufp) { const int go = (t) * 128 + (kh) * 64; \
    GL2LDS(B0p + go, (bufp) + 32768 + (kh) * 16384 + dst); \
    GL2LDS(B1p + go, (bufp) + 32768 + (kh) * 16384 + 8192 + dst); }

  // prologue: tile 0 -> buf0, issue order = steady-state queue order
  SU_A(0, 0, lds); SU_B(0, 0, lds); SU_A(0, 1, lds); SU_B(0, 1, lds);

#pragma unroll 1
  for (int t = 0; t < NT; ++t) {
    char* cur = lds + ((t & 1) << 16);
    char* nb  = lds + (((t + 1) & 1) << 16);
    const bool pre = (t + 1 < NT);
    bf16x8 a[8], bv0, bv1, bv2, bv3;

    // ---------------- P1: kh0, n0/n1 ----------------
    __builtin_amdgcn_sched_barrier(0);
    asm volatile("s_waitcnt vmcnt(4)" ::: "memory");
    __builtin_amdgcn_s_barrier();
    __builtin_amdgcn_sched_barrier(0);
    if (pre) SU_A(t + 1, 0, nb);
#pragma unroll
    for (int m = 0; m < 8; ++m) a[m] = *(const bf16x8*)(cur + abase + m * 1024);
    bv0 = *(const bf16x8*)(cur + bbase);
    bv1 = *(const bf16x8*)(cur + bbase + 1024);
    __builtin_amdgcn_s_setprio(1);
#pragma unroll
    for (int m = 0; m < 8; ++m) {
      acc[m][0] = MFMA16(a[m], bv0, acc[m][0]);
      acc[m][1] = MFMA16(a[m], bv1, acc[m][1]);
    }
    __builtin_amdgcn_s_setprio(0);

    // ---------------- P2: kh0, n2/n3 ----------------
    if (pre) SU_B(t + 1, 0, nb);
    bv2 = *(const bf16x8*)(cur + bbase + 2048);
    bv3 = *(const bf16x8*)(cur + bbase + 3072);
    __builtin_amdgcn_s_setprio(1);
#pragma unroll
    for (int m = 0; m < 8; ++m) {
      acc[m][2] = MFMA16(a[m], bv2, acc[m][2]);
      acc[m][3] = MFMA16(a[m], bv3, acc[m][3]);
    }
    __builtin_amdgcn_s_setprio(0);

    // ---------------- P3: kh1, n0/n1 ----------------
    __builtin_amdgcn_sched_barrier(0);
    if (pre) asm volatile("s_waitcnt vmcnt(4)" ::: "memory");
    else     asm volatile("s_waitcnt vmcnt(0)" ::: "memory");
    __builtin_amdgcn_s_barrier();
    __builtin_amdgcn_sched_barrier(0);
    if (pre) SU_A(t + 1, 1, nb);
#pragma unroll
    for (int m = 0; m < 8; ++m) a[m] = *(const bf16x8*)(cur + abase + 16384 + m * 1024);
    bv0 = *(const bf16x8*)(cur + bbase + 16384);
    bv1 = *(const bf16x8*)(cur + bbase + 16384 + 1024);
    __builtin_amdgcn_s_setprio(1);
#pragma unroll
    for (int m = 0; m < 8; ++m) {
      acc[m][0] = MFMA16(a[m], bv0, acc[m][0]);
      acc[m][1] = MFMA16(a[m], bv1, acc[m][1]);
    }
    __builtin_amdgcn_s_setprio(0);

    // ---------------- P4: kh1, n2/n3 ----------------
    if (pre) SU_B(t + 1, 1, nb);
    bv2 = *(const bf16x8*)(cur + bbase + 16384 + 2048);
    bv3 = *(const bf16x8*)(cur + bbase + 16384 + 3072);
    __builtin_amdgcn_s_setprio(1);
#pragma unroll
    for (int m = 0; m < 8; ++m) {
      acc[m][2] = MFMA16(a[m], bv2, acc[m][2]);
      acc[m][3] = MFMA16(a[m], bv3, acc[m][3]);
    }
    __builtin_amdgcn_s_setprio(0);
  }
#undef SU_A
#undef SU_B
}

// ---------------- GEMM1: H[p][s][h] = gelu(x @ w1 + b1)  (A = weights) ----------------
__global__ __launch_bounds__(512, 2) void gemm1_kernel(
    const __hip_bfloat16* __restrict__ Xb, const __hip_bfloat16* __restrict__ W1T,
    const float* __restrict__ b1, __hip_bfloat16* __restrict__ Hbuf,
    const int* __restrict__ gidx, const int* __restrict__ psort)
{
  extern __shared__ char lds[];
  const int P = blockIdx.x;                 // 1024
  const int L = (P & 7) * 128 + (P >> 3);   // bijective XCD chunk remap
  const int p = psort[L >> 4];              // 16 tiles/pair, pair-clustered per XCD
  const int tl = L & 15;
  const int b = p >> 1;
  const int e = gidx[p];
  const int h0 = (tl >> 1) * 256;           // 8 h-tiles
  const int s0 = (tl & 1) * 256;            // 2 s-tiles
  const char* Ag = (const char*)W1T + ((size_t)e * H_ + h0) * D_ * 2;
  const char* Bg = (const char*)Xb + ((size_t)b * S_ + s0) * D_ * 2;
  f32x4 acc[8][4] = {};
  gemm_core_v3(Ag, Bg, D_ * 2, D_ * 2, D_ / 64, lds, acc);

  const int tid = threadIdx.x, l = tid & 63, w = tid >> 6;
  const int wm = w >> 2, wn = w & 3, lr = l & 15, q4 = ((l >> 4) & 3) << 2;
  const float* b1e = b1 + (size_t)e * H_ + h0;
  __hip_bfloat16* Hp = Hbuf + (size_t)p * S_ * H_ + h0;
#pragma unroll
  for (int m = 0; m < 8; ++m) {
    const int hl = wm * 128 + m * 16 + q4;          // feature offset (mult of 4)
    const float4 bias = *(const float4*)(b1e + hl);
#pragma unroll
    for (int n = 0; n < 4; ++n) {
      const int sl = s0 + wn * 64 + n * 16 + lr;    // s row
      ushort4 ov;
      ov.x = __builtin_bit_cast(unsigned short, __float2bfloat16(gelu_fast(acc[m][n][0] + bias.x)));
      ov.y = __builtin_bit_cast(unsigned short, __float2bfloat16(gelu_fast(acc[m][n][1] + bias.y)));
      ov.z = __builtin_bit_cast(unsigned short, __float2bfloat16(gelu_fast(acc[m][n][2] + bias.z)));
      ov.w = __builtin_bit_cast(unsigned short, __float2bfloat16(gelu_fast(acc[m][n][3] + bias.w)));
      *(ushort4*)(Hp + (size_t)sl * H_ + hl) = ov;
    }
  }
}

// ---------------- GEMM2: out[b][s][o] += gw * gelu(H @ w2 + b2)  (A = data) ----------------
// A = Hbuf s-rows -> acc m-axis = s (j along s); B = W2T o-rows -> n-axis = o,
// 16 lanes (lr) cover 16 consecutive o -> line-friendly scalar atomics
// (r1-proven pattern, WRITE ~65 MB). 2 deterministic f32 atomic terms/output.
__global__ __launch_bounds__(512, 2) void gemm2_kernel(
    const __hip_bfloat16* __restrict__ Hbuf, const __hip_bfloat16* __restrict__ W2T,
    const float* __restrict__ b2, float* __restrict__ out,
    const int* __restrict__ gidx, const float* __restrict__ gwt,
    const int* __restrict__ psort)
{
  extern __shared__ char lds[];
  const int P = blockIdx.x;                 // 256 (1/CU)
  const int L = (P & 7) * 32 + (P >> 3);
  const int p = psort[L >> 2];              // 4 tiles/pair, expert-clustered per XCD
  const int tl = L & 3;
  const int b = p >> 1;
  const int e = gidx[p];
  const float gw = gwt[p];
  const int s0 = (tl >> 1) * 256;           // 2 s-tiles
  const int o0 = (tl & 1) * 256;            // 2 o-tiles
  const char* Ag = (const char*)Hbuf + ((size_t)p * S_ + s0) * H_ * 2;
  const char* Bg = (const char*)W2T + ((size_t)e * O_ + o0) * H_ * 2;
  f32x4 acc[8][4] = {};
  gemm_core_v3(Ag, Bg, H_ * 2, H_ * 2, H_ / 64, lds, acc);

  const int tid = threadIdx.x, l = tid & 63, w = tid >> 6;
  const int wm = w >> 2, wn = w & 3, lr = l & 15, q4 = ((l >> 4) & 3) << 2;
  const float* b2e = b2 + (size_t)e * O_ + o0;
#pragma unroll
  for (int m = 0; m < 8; ++m) {
    const int sl = s0 + wm * 128 + m * 16 + q4;     // s base for j=0..3
#pragma unroll
    for (int n = 0; n < 4; ++n) {
      const int ol = wn * 64 + n * 16 + lr;         // o (16 consecutive per lane group)
      const float bias = b2e[ol];
      float* dstp = out + ((size_t)b * S_ + sl) * O_ + o0 + ol;
#pragma unroll
      for (int j = 0; j < 4; ++j)
        atomicAdd(dstp + (size_t)j * O_, gelu_fast(acc[m][n][j] + bias) * gw);
    }
  }
}

// ---------------- sentinel (ws too small signal) ----------------
__global__ void sentinel_kernel(float* out, int n) {
  int i = blockIdx.x * blockDim.x + threadIdx.x;
  for (; i < n; i += gridDim.x * blockDim.x) out[i] = 1.0e6f;
}

extern "C" void kernel_launch(void* const* d_in, const int* in_sizes, int n_in,
                              void* d_out, int out_size, void* d_ws, size_t ws_size,
                              hipStream_t stream)
{
  const float* x      = (const float*)d_in[0];
  const float* attn_w = (const float*)d_in[1];
  // d_in[2] = attn_b: scalar, softmax-invariant -> unused
  const float* gate_w = (const float*)d_in[3];
  const float* gate_b = (const float*)d_in[4];
  const float* w1     = (const float*)d_in[5];
  const float* b1     = (const float*)d_in[6];
  const float* w2     = (const float*)d_in[7];
  const float* b2     = (const float*)d_in[8];
  float* out = (float*)d_out;

  char* ws = (char*)d_ws;
  const size_t OFF_GIDX = 0;     // 256 B
  const size_t OFF_GWT  = 256;   // 256 B
  const size_t OFF_PSRT = 512;   // 256 B
  const size_t OFF_X    = 1024;
  const size_t SZ_X     = (size_t)B_ * S_ * D_ * 2;   // 16 MB
  const size_t OFF_W1T  = OFF_X + SZ_X;
  const size_t SZ_W1T   = (size_t)E_ * H_ * D_ * 2;   // 16 MB
  const size_t OFF_W2T  = OFF_W1T + SZ_W1T;
  const size_t SZ_W2T   = (size_t)E_ * O_ * H_ * 2;   // 16 MB
  const size_t OFF_H    = OFF_W2T + SZ_W2T;
  const size_t PAIR_H   = (size_t)S_ * H_ * 2;        // 2 MB per pair

  if (OFF_H + 64 * PAIR_H > ws_size) {
    hipLaunchKernelGGL(sentinel_kernel, dim3(256), dim3(256), 0, stream, out, out_size);
    return;
  }

  int*   gidx  = (int*)(ws + OFF_GIDX);
  float* gwt   = (float*)(ws + OFF_GWT);
  int*   psort = (int*)(ws + OFF_PSRT);
  __hip_bfloat16* xb   = (__hip_bfloat16*)(ws + OFF_X);
  __hip_bfloat16* w1T  = (__hip_bfloat16*)(ws + OFF_W1T);
  __hip_bfloat16* w2T  = (__hip_bfloat16*)(ws + OFF_W2T);
  __hip_bfloat16* Hbuf = (__hip_bfloat16*)(ws + OFF_H);
  // pool-chain scratch overlaid on Hbuf region (consumed before gemm1 writes it)
  float* scores = (float*)(ws + OFF_H);            // 64 KB
  float* aw     = (float*)(ws + OFF_H + 65536);    // 64 KB
  float* pooled = (float*)(ws + OFF_H + 131072);   // 64 KB

  // 128 KiB dynamic LDS opt-in
  (void)hipFuncSetAttribute((const void*)gemm1_kernel, hipFuncAttributeMaxDynamicSharedMemorySize, 131072);
  (void)hipFuncSetAttribute((const void*)gemm2_kernel, hipFuncAttributeMaxDynamicSharedMemorySize, 131072);

  hipLaunchKernelGGL(cast_score_kernel, dim3(B_ * S_ / 8), dim3(256), 0, stream,
                     x, attn_w, (ushort*)xb, scores);
  hipLaunchKernelGGL(softmax_aw_kernel, dim3(B_), dim3(512), 0, stream, scores, aw);
  hipLaunchKernelGGL(pool_kernel, dim3(4, B_), dim3(512), 0, stream, x, aw, pooled);
  hipLaunchKernelGGL(gate_psort_kernel, dim3(1), dim3(256), 0, stream,
                     pooled, gate_w, gate_b, gidx, gwt, psort);
  hipLaunchKernelGGL(transpose_cast_kernel, dim3(H_ / 32, D_ / 32, E_), dim3(32, 8), 0, stream,
                     w1, w1T, D_, H_);
  hipLaunchKernelGGL(transpose_cast_kernel, dim3(O_ / 32, H_ / 32, E_), dim3(32, 8), 0, stream,
                     w2, w2T, H_, O_);
  hipMemsetAsync(d_out, 0, (size_t)out_size * sizeof(float), stream);

  hipLaunchKernelGGL(gemm1_kernel, dim3(1024), dim3(512), 131072, stream,
                     xb, w1T, b1, Hbuf, gidx, psort);
  hipLaunchKernelGGL(gemm2_kernel, dim3(256), dim3(512), 131072, stream,
                     Hbuf, w2T, b2, out, gidx, gwt, psort);
}

// Round 8
// 268.439 us; speedup vs baseline: 1.6562x; 1.0809x over previous
//
#include <hip/hip_runtime.h>
#include <hip/hip_bf16.h>
#include <math.h>

#define B_  32
#define S_  512
#define D_  512
#define E_  8
#define H_  2048
#define O_  512

typedef __bf16 bf16x8 __attribute__((ext_vector_type(8)));
typedef float  f32x4  __attribute__((ext_vector_type(4)));

#define GL2LDS(src, dst) \
  __builtin_amdgcn_global_load_lds((const __attribute__((address_space(1))) void*)(src), \
                                   (__attribute__((address_space(3))) void*)(dst), 16, 0, 0)

#define MFMA16(a, b, c) __builtin_amdgcn_mfma_f32_16x16x32_bf16((a), (b), (c), 0, 0, 0)

// tanh-form GELU (proven r4-r7: absmax 3.9e-3 unchanged)
__device__ __forceinline__ float gelu_fast(float v) {
  float w = v * fmaf(v * v, 0.0713548162f, 1.5957691216f);
  float e = __expf(-w);
  return v * __builtin_amdgcn_rcpf(1.0f + e);
}

// =====================================================================
// Packed operand layout (NEW r8): [z][kt][kh][rows][64B], with the 16B slot
// within each 64B row pre-swizzled: phys_slot = ks ^ ((row>>1)&3).
// Stage-units (256 rows x 64B = 16KB) are fully contiguous -> every
// global_load_lds is a contiguous 1KB lane-linear copy (m97 pattern).
// ds_read applies the same swizzle (r7 axor, unchanged).
// =====================================================================

// ---------------- cast x -> packed bf16 (xpack), fused attention scores ----
__global__ __launch_bounds__(256) void cast_score_kernel(
    const float* __restrict__ x, const float* __restrict__ attn_w,
    char* __restrict__ xpack, float* __restrict__ scores)
{
  const int t = threadIdx.x;
  const int r = t >> 5;
  const int cg = t & 31;
  const int row = blockIdx.x * 8 + r;     // global b*512+s
  const int bb = row >> 9, s = row & 511;
  const float* src  = x + (size_t)row * D_ + cg * 16;
  const float* wsrc = attn_w + cg * 16;
  char* xp = xpack + (size_t)bb * 524288 + s * 64;   // + kt2*32768 + slot*16 + (d&7)*2
  const int sx = (s >> 1) & 3;
  float acc = 0.f;
#pragma unroll
  for (int k = 0; k < 4; ++k) {
    const int d0 = cg * 16 + k * 4;
    float4 v  = *(const float4*)(src + k * 4);
    float4 wv = *(const float4*)(wsrc + k * 4);
    acc += v.x * wv.x + v.y * wv.y + v.z * wv.z + v.w * wv.w;
    ushort4 o;
    o.x = __builtin_bit_cast(unsigned short, __float2bfloat16(v.x));
    o.y = __builtin_bit_cast(unsigned short, __float2bfloat16(v.y));
    o.z = __builtin_bit_cast(unsigned short, __float2bfloat16(v.z));
    o.w = __builtin_bit_cast(unsigned short, __float2bfloat16(v.w));
    const int kt2 = ((d0 >> 6) << 1) | ((d0 >> 5) & 1);
    const int byte = kt2 * 32768 + ((((d0 >> 3) & 3) ^ sx) << 4) + (d0 & 7) * 2;
    *(ushort4*)(xp + byte) = o;
  }
#pragma unroll
  for (int off = 16; off; off >>= 1) acc += __shfl_xor(acc, off);
  if (cg == 0) scores[row] = acc;
}

// ---------------- softmax over S per batch -> aw ----------------
__global__ __launch_bounds__(512) void softmax_aw_kernel(
    const float* __restrict__ scores, float* __restrict__ aw)
{
  __shared__ float red[8];
  __shared__ float mm, ss;
  const int t = threadIdx.x, b = blockIdx.x;
  float v = scores[b * S_ + t];
  float m = v;
#pragma unroll
  for (int off = 32; off; off >>= 1) m = fmaxf(m, __shfl_xor(m, off));
  if ((t & 63) == 0) red[t >> 6] = m;
  __syncthreads();
  if (t == 0) {
    float a = red[0];
    for (int i = 1; i < 8; ++i) a = fmaxf(a, red[i]);
    mm = a;
  }
  __syncthreads();
  float e = expf(v - mm);
  float s = e;
#pragma unroll
  for (int off = 32; off; off >>= 1) s += __shfl_xor(s, off);
  if ((t & 63) == 0) red[t >> 6] = s;
  __syncthreads();
  if (t == 0) {
    float a = 0.f;
    for (int i = 0; i < 8; ++i) a += red[i];
    ss = 1.f / a;
  }
  __syncthreads();
  aw[b * S_ + t] = e * ss;
}

// ---------------- pooled[b,d] = sum_s aw[b,s] * x[b,s,d] (f32, exact) ----------------
__global__ __launch_bounds__(512) void pool_kernel(
    const float* __restrict__ x, const float* __restrict__ aw, float* __restrict__ pooled)
{
  __shared__ float sm[4][128];
  const int t = threadIdx.x;
  const int dl = t & 127;
  const int sh = t >> 7;
  const int b = blockIdx.y;
  const int d = blockIdx.x * 128 + dl;
  const float* xp  = x + (size_t)b * S_ * D_ + d;
  const float* awb = aw + b * S_;
  float acc = 0.f;
#pragma unroll 4
  for (int s = sh; s < S_; s += 4)
    acc = fmaf(awb[s], xp[(size_t)s * D_], acc);
  if (sh) sm[sh][dl] = acc;
  __syncthreads();
  if (sh == 0) pooled[b * D_ + d] = acc + sm[1][dl] + sm[2][dl] + sm[3][dl];
}

// ---------------- gates + top-2 + renorm + expert-sort ----------------
__global__ __launch_bounds__(256) void gate_psort_kernel(
    const float* __restrict__ pooled, const float* __restrict__ gate_w,
    const float* __restrict__ gate_b, int* __restrict__ gidx, float* __restrict__ gwt,
    int* __restrict__ psort)
{
  __shared__ float gl[32][8];
  const int t = threadIdx.x;
  const int b = t >> 3, ee = t & 7;
  float z = gate_b[ee];
  const float* pb = pooled + b * D_;
  for (int d = 0; d < D_; ++d) z = fmaf(pb[d], gate_w[d * E_ + ee], z);
  gl[b][ee] = z;
  __syncthreads();
  if (t < 32) {
    float ge[8];
    float zmax = gl[t][0];
    for (int i = 1; i < 8; ++i) zmax = fmaxf(zmax, gl[t][i]);
    float zs = 0.f;
    for (int i = 0; i < 8; ++i) { ge[i] = expf(gl[t][i] - zmax); zs += ge[i]; }
    for (int i = 0; i < 8; ++i) ge[i] /= zs;
    int i0 = 0;
    for (int i = 1; i < 8; ++i) if (ge[i] > ge[i0]) i0 = i;
    int i1 = -1;
    for (int i = 0; i < 8; ++i) if (i != i0 && (i1 < 0 || ge[i] > ge[i1])) i1 = i;
    float denom = ge[i0] + ge[i1] + 1e-9f;
    gidx[t * 2 + 0] = i0; gidx[t * 2 + 1] = i1;
    gwt[t * 2 + 0] = ge[i0] / denom; gwt[t * 2 + 1] = ge[i1] / denom;
  }
  __syncthreads();
  if (t == 0) {
    int cnt[E_] = {}, pos[E_];
    for (int p = 0; p < 2 * B_; ++p) cnt[gidx[p]]++;
    int s = 0;
    for (int e2 = 0; e2 < E_; ++e2) { pos[e2] = s; s += cnt[e2]; }
    for (int p = 0; p < 2 * B_; ++p) psort[pos[gidx[p]]++] = p;
  }
}

// ---------------- weight pack: [z][R k][C rows] f32 -> packed bf16 ----------------
// out[z][kt(k)][kh(k)][row=c][64B] with pre-swizzled slot; PAN = C*64 bytes.
__global__ void pack_w_kernel(const float* __restrict__ in, char* __restrict__ outp,
                              int R, int C)
{
  __shared__ float tile[32][33];
  const int z = blockIdx.z;
  const float* inz = in + (size_t)z * R * C;
  const int c0 = blockIdx.x * 32, r0 = blockIdx.y * 32;
  const int tx = threadIdx.x, ty = threadIdx.y;
#pragma unroll
  for (int jj = 0; jj < 4; ++jj) {
    int r = r0 + ty + jj * 8;
    tile[ty + jj * 8][tx] = inz[(size_t)r * C + c0 + tx];
  }
  __syncthreads();
  const int k = r0 + tx;                                // contraction index
  const int kt2 = ((k >> 6) << 1) | ((k >> 5) & 1);     // constant over tile (r0%32==0)
  const int PAN = C * 64;
  char* oz = outp + (size_t)z * R * C * 2 + (size_t)kt2 * PAN;
  const int kslot = (k >> 3) & 3;
  const int kbyte = (k & 7) * 2;
#pragma unroll
  for (int jj = 0; jj < 4; ++jj) {
    const int row = c0 + ty + jj * 8;
    const int byte = row * 64 + ((kslot ^ ((row >> 1) & 3)) << 4) + kbyte;
    *(ushort*)(oz + byte) =
        __builtin_bit_cast(unsigned short, __float2bfloat16(tile[tx][ty + jj * 8]));
  }
}

// =====================================================================
// GEMM core v4: identical schedule/ledger/swizzle to r7 (verified), but all
// stage-units are contiguous 16KB packed panels -> each GL2LDS is a
// contiguous 1KB lane-linear copy. panelA/panelB = byte stride per (kt,kh).
// =====================================================================
__device__ __forceinline__ void gemm_core_v4(const char* __restrict__ Ag, const char* __restrict__ Bg,
                                             const int panelA, const int panelB, const int NT,
                                             char* lds, f32x4 (&acc)[8][4])
{
  const int tid = threadIdx.x;
  const int l = tid & 63;
  const int w = tid >> 6;
  const int wm = w >> 2;
  const int wn = w & 3;
  const int lr = l & 15;
  const int ks = (l >> 4) & 3;
  const int axor = ((ks ^ ((lr >> 1) & 3)) << 4);
  const int abase = (wm * 128 + lr) * 64 + axor;           // + kh*16384 + m*1024
  const int bbase = 32768 + (wn * 64 + lr) * 64 + axor;    // + kh*16384 + n*1024
  const int dst = tid * 16;

#define SU_A(t, kh, bufp) { const char* s_ = Ag + (size_t)((t) * 2 + (kh)) * panelA; \
    GL2LDS(s_ + dst,        (bufp) + (kh) * 16384 + dst); \
    GL2LDS(s_ + 8192 + dst, (bufp) + (kh) * 16384 + 8192 + dst); }
#define SU_B(t, kh, bufp) { const char* s_ = Bg + (size_t)((t) * 2 + (kh)) * panelB; \
    GL2LDS(s_ + dst,        (bufp) + 32768 + (kh) * 16384 + dst); \
    GL2LDS(s_ + 8192 + dst, (bufp) + 32768 + (kh) * 16384 + 8192 + dst); }

  // prologue: tile 0 -> buf0, issue order = steady-state queue order
  SU_A(0, 0, lds); SU_B(0, 0, lds); SU_A(0, 1, lds); SU_B(0, 1, lds);

#pragma unroll 1
  for (int t = 0; t < NT; ++t) {
    char* cur = lds + ((t & 1) << 16);
    char* nb  = lds + (((t + 1) & 1) << 16);
    const bool pre = (t + 1 < NT);
    bf16x8 a[8], bv0, bv1, bv2, bv3;

    // ---------------- P1: kh0, n0/n1 ----------------
    __builtin_amdgcn_sched_barrier(0);
    asm volatile("s_waitcnt vmcnt(4)" ::: "memory");
    __builtin_amdgcn_s_barrier();
    __builtin_amdgcn_sched_barrier(0);
    if (pre) SU_A(t + 1, 0, nb);
#pragma unroll
    for (int m = 0; m < 8; ++m) a[m] = *(const bf16x8*)(cur + abase + m * 1024);
    bv0 = *(const bf16x8*)(cur + bbase);
    bv1 = *(const bf16x8*)(cur + bbase + 1024);
    __builtin_amdgcn_s_setprio(1);
#pragma unroll
    for (int m = 0; m < 8; ++m) {
      acc[m][0] = MFMA16(a[m], bv0, acc[m][0]);
      acc[m][1] = MFMA16(a[m], bv1, acc[m][1]);
    }
    __builtin_amdgcn_s_setprio(0);

    // ---------------- P2: kh0, n2/n3 ----------------
    if (pre) SU_B(t + 1, 0, nb);
    bv2 = *(const bf16x8*)(cur + bbase + 2048);
    bv3 = *(const bf16x8*)(cur + bbase + 3072);
    __builtin_amdgcn_s_setprio(1);
#pragma unroll
    for (int m = 0; m < 8; ++m) {
      acc[m][2] = MFMA16(a[m], bv2, acc[m][2]);
      acc[m][3] = MFMA16(a[m], bv3, acc[m][3]);
    }
    __builtin_amdgcn_s_setprio(0);

    // ---------------- P3: kh1, n0/n1 ----------------
    __builtin_amdgcn_sched_barrier(0);
    if (pre) asm volatile("s_waitcnt vmcnt(4)" ::: "memory");
    else     asm volatile("s_waitcnt vmcnt(0)" ::: "memory");
    __builtin_amdgcn_s_barrier();
    __builtin_amdgcn_sched_barrier(0);
    if (pre) SU_A(t + 1, 1, nb);
#pragma unroll
    for (int m = 0; m < 8; ++m) a[m] = *(const bf16x8*)(cur + abase + 16384 + m * 1024);
    bv0 = *(const bf16x8*)(cur + bbase + 16384);
    bv1 = *(const bf16x8*)(cur + bbase + 16384 + 1024);
    __builtin_amdgcn_s_setprio(1);
#pragma unroll
    for (int m = 0; m < 8; ++m) {
      acc[m][0] = MFMA16(a[m], bv0, acc[m][0]);
      acc[m][1] = MFMA16(a[m], bv1, acc[m][1]);
    }
    __builtin_amdgcn_s_setprio(0);

    // ---------------- P4: kh1, n2/n3 ----------------
    if (pre) SU_B(t + 1, 1, nb);
    bv2 = *(const bf16x8*)(cur + bbase + 16384 + 2048);
    bv3 = *(const bf16x8*)(cur + bbase + 16384 + 3072);
    __builtin_amdgcn_s_setprio(1);
#pragma unroll
    for (int m = 0; m < 8; ++m) {
      acc[m][2] = MFMA16(a[m], bv2, acc[m][2]);
      acc[m][3] = MFMA16(a[m], bv3, acc[m][3]);
    }
    __builtin_amdgcn_s_setprio(0);
  }
#undef SU_A
#undef SU_B
}

// ---------------- GEMM1: Hpack = gelu(x @ w1 + b1)  (A = weights) ----------------
__global__ __launch_bounds__(512, 2) void gemm1_kernel(
    const char* __restrict__ xpack, const char* __restrict__ W1pack,
    const float* __restrict__ b1, char* __restrict__ Hpack,
    const int* __restrict__ gidx, const int* __restrict__ psort)
{
  extern __shared__ char lds[];
  const int P = blockIdx.x;                 // 1024
  const int L = (P & 7) * 128 + (P >> 3);   // bijective XCD chunk remap
  const int p = psort[L >> 4];              // 16 tiles/pair, pair-clustered per XCD
  const int tl = L & 15;
  const int b = p >> 1;
  const int e = gidx[p];
  const int h0 = (tl >> 1) * 256;           // 8 h-tiles
  const int s0 = (tl & 1) * 256;            // 2 s-tiles
  const char* Ag = W1pack + (size_t)e * 2097152 + h0 * 64;  // panelA = 2048*64
  const char* Bg = xpack + (size_t)b * 524288 + s0 * 64;    // panelB = 512*64
  f32x4 acc[8][4] = {};
  gemm_core_v4(Ag, Bg, 131072, 32768, D_ / 64, lds, acc);

  const int tid = threadIdx.x, l = tid & 63, w = tid >> 6;
  const int wm = w >> 2, wn = w & 3, lr = l & 15, q4 = ((l >> 4) & 3) << 2;
  const float* b1e = b1 + (size_t)e * H_ + h0;
  char* Hp = Hpack + (size_t)p * 2097152;
#pragma unroll
  for (int m = 0; m < 8; ++m) {
    const int hl = wm * 128 + m * 16 + q4;          // feature offset (mult of 4)
    const int h = h0 + hl;
    const int kt2h = ((h >> 6) << 1) | ((h >> 5) & 1);
    const int hslot = (h >> 3) & 3;
    const int hbyte = (h & 7) * 2;
    const float4 bias = *(const float4*)(b1e + hl);
#pragma unroll
    for (int n = 0; n < 4; ++n) {
      const int sl = s0 + wn * 64 + n * 16 + lr;    // s row
      ushort4 ov;
      ov.x = __builtin_bit_cast(unsigned short, __float2bfloat16(gelu_fast(acc[m][n][0] + bias.x)));
      ov.y = __builtin_bit_cast(unsigned short, __float2bfloat16(gelu_fast(acc[m][n][1] + bias.y)));
      ov.z = __builtin_bit_cast(unsigned short, __float2bfloat16(gelu_fast(acc[m][n][2] + bias.z)));
      ov.w = __builtin_bit_cast(unsigned short, __float2bfloat16(gelu_fast(acc[m][n][3] + bias.w)));
      const int byte = kt2h * 32768 + sl * 64 + ((hslot ^ ((sl >> 1) & 3)) << 4) + hbyte;
      *(ushort4*)(Hp + byte) = ov;
    }
  }
}

// ---------------- GEMM2: out += gw * gelu(H @ w2 + b2)  (A = data) ----------------
// j-axis along s, 16 lanes cover 16 consecutive o -> line-friendly atomics
// (r7-verified: WRITE 65 MB). 2 deterministic f32 atomic terms/output.
__global__ __launch_bounds__(512, 2) void gemm2_kernel(
    const char* __restrict__ Hpack, const char* __restrict__ W2pack,
    const float* __restrict__ b2, float* __restrict__ out,
    const int* __restrict__ gidx, const float* __restrict__ gwt,
    const int* __restrict__ psort)
{
  extern __shared__ char lds[];
  const int P = blockIdx.x;                 // 256 (1/CU)
  const int L = (P & 7) * 32 + (P >> 3);
  const int p = psort[L >> 2];              // 4 tiles/pair, expert-clustered per XCD
  const int tl = L & 3;
  const int b = p >> 1;
  const int e = gidx[p];
  const float gw = gwt[p];
  const int s0 = (tl >> 1) * 256;           // 2 s-tiles
  const int o0 = (tl & 1) * 256;            // 2 o-tiles
  const char* Ag = Hpack + (size_t)p * 2097152 + s0 * 64;   // panelA = 512*64
  const char* Bg = W2pack + (size_t)e * 2097152 + o0 * 64;  // panelB = 512*64
  f32x4 acc[8][4] = {};
  gemm_core_v4(Ag, Bg, 32768, 32768, H_ / 64, lds, acc);

  const int tid = threadIdx.x, l = tid & 63, w = tid >> 6;
  const int wm = w >> 2, wn = w & 3, lr = l & 15, q4 = ((l >> 4) & 3) << 2;
  const float* b2e = b2 + (size_t)e * O_ + o0;
#pragma unroll
  for (int m = 0; m < 8; ++m) {
    const int sl = s0 + wm * 128 + m * 16 + q4;     // s base for j=0..3
#pragma unroll
    for (int n = 0; n < 4; ++n) {
      const int ol = wn * 64 + n * 16 + lr;         // o (16 consecutive per lane group)
      const float bias = b2e[ol];
      float* dstp = out + ((size_t)b * S_ + sl) * O_ + o0 + ol;
#pragma unroll
      for (int j = 0; j < 4; ++j)
        atomicAdd(dstp + (size_t)j * O_, gelu_fast(acc[m][n][j] + bias) * gw);
    }
  }
}

// ---------------- sentinel (ws too small signal) ----------------
__global__ void sentinel_kernel(float* out, int n) {
  int i = blockIdx.x * blockDim.x + threadIdx.x;
  for (; i < n; i += gridDim.x * blockDim.x) out[i] = 1.0e6f;
}

extern "C" void kernel_launch(void* const* d_in, const int* in_sizes, int n_in,
                              void* d_out, int out_size, void* d_ws, size_t ws_size,
                              hipStream_t stream)
{
  const float* x      = (const float*)d_in[0];
  const float* attn_w = (const float*)d_in[1];
  // d_in[2] = attn_b: scalar, softmax-invariant -> unused
  const float* gate_w = (const float*)d_in[3];
  const float* gate_b = (const float*)d_in[4];
  const float* w1     = (const float*)d_in[5];
  const float* b1     = (const float*)d_in[6];
  const float* w2     = (const float*)d_in[7];
  const float* b2     = (const float*)d_in[8];
  float* out = (float*)d_out;

  char* ws = (char*)d_ws;
  const size_t OFF_GIDX = 0;     // 256 B
  const size_t OFF_GWT  = 256;   // 256 B
  const size_t OFF_PSRT = 512;   // 256 B
  const size_t OFF_X    = 1024;
  const size_t SZ_X     = (size_t)B_ * S_ * D_ * 2;   // 16 MB (xpack)
  const size_t OFF_W1T  = OFF_X + SZ_X;
  const size_t SZ_W1T   = (size_t)E_ * H_ * D_ * 2;   // 16 MB (W1pack)
  const size_t OFF_W2T  = OFF_W1T + SZ_W1T;
  const size_t SZ_W2T   = (size_t)E_ * O_ * H_ * 2;   // 16 MB (W2pack)
  const size_t OFF_H    = OFF_W2T + SZ_W2T;
  const size_t PAIR_H   = (size_t)S_ * H_ * 2;        // 2 MB per pair (Hpack)

  if (OFF_H + 64 * PAIR_H > ws_size) {
    hipLaunchKernelGGL(sentinel_kernel, dim3(256), dim3(256), 0, stream, out, out_size);
    return;
  }

  int*   gidx   = (int*)(ws + OFF_GIDX);
  float* gwt    = (float*)(ws + OFF_GWT);
  int*   psort  = (int*)(ws + OFF_PSRT);
  char*  xpack  = ws + OFF_X;
  char*  W1pack = ws + OFF_W1T;
  char*  W2pack = ws + OFF_W2T;
  char*  Hpack  = ws + OFF_H;
  // pool-chain scratch overlaid on Hpack region (consumed before gemm1 writes it)
  float* scores = (float*)(ws + OFF_H);            // 64 KB
  float* aw     = (float*)(ws + OFF_H + 65536);    // 64 KB
  float* pooled = (float*)(ws + OFF_H + 131072);   // 64 KB

  // 128 KiB dynamic LDS opt-in
  (void)hipFuncSetAttribute((const void*)gemm1_kernel, hipFuncAttributeMaxDynamicSharedMemorySize, 131072);
  (void)hipFuncSetAttribute((const void*)gemm2_kernel, hipFuncAttributeMaxDynamicSharedMemorySize, 131072);

  hipLaunchKernelGGL(cast_score_kernel, dim3(B_ * S_ / 8), dim3(256), 0, stream,
                     x, attn_w, xpack, scores);
  hipLaunchKernelGGL(softmax_aw_kernel, dim3(B_), dim3(512), 0, stream, scores, aw);
  hipLaunchKernelGGL(pool_kernel, dim3(4, B_), dim3(512), 0, stream, x, aw, pooled);
  hipLaunchKernelGGL(gate_psort_kernel, dim3(1), dim3(256), 0, stream,
                     pooled, gate_w, gate_b, gidx, gwt, psort);
  // w1: [e][R=512 d][C=2048 h] -> W1pack; w2: [e][R=2048 h][C=512 o] -> W2pack
  hipLaunchKernelGGL(pack_w_kernel, dim3(H_ / 32, D_ / 32, E_), dim3(32, 8), 0, stream,
                     w1, W1pack, D_, H_);
  hipLaunchKernelGGL(pack_w_kernel, dim3(O_ / 32, H_ / 32, E_), dim3(32, 8), 0, stream,
                     w2, W2pack, H_, O_);
  hipMemsetAsync(d_out, 0, (size_t)out_size * sizeof(float), stream);

  hipLaunchKernelGGL(gemm1_kernel, dim3(1024), dim3(512), 131072, stream,
                     xpack, W1pack, b1, Hpack, gidx, psort);
  hipLaunchKernelGGL(gemm2_kernel, dim3(256), dim3(512), 131072, stream,
                     Hpack, W2pack, b2, out, gidx, gwt, psort);
}